// Round 18
// baseline (73.615 us; speedup 1.0000x reference)
//
#include <hip/hip_runtime.h>
#include <math.h>

#define TNODES 8192
#define CC 128
#define RT2 32       // rows per block for k2 (512 threads, 8 waves)
#define RT5 16       // srcs per block for k45 (256 threads, 4 waves x 4 srcs; 2 blocks/CU)
#define DEGCAP 128   // bucket capacity per src; degrees ~Poisson(39)+1, max~70

typedef __attribute__((ext_vector_type(8))) short bf8;
typedef __attribute__((ext_vector_type(4))) float fx4;
typedef __attribute__((ext_vector_type(2))) float fv2;

__device__ __forceinline__ ushort f2b(float f){
  union { float f; uint u; } a; a.f = f;
  uint u = a.u;
  uint r = (u + 0x7fffu + ((u >> 16) & 1u)) >> 16;   // RNE
  return (ushort)r;
}
__device__ __forceinline__ float b2f(ushort s){
  union { uint u; float f; } a; a.u = ((uint)s) << 16;
  return a.f;
}
__device__ __forceinline__ float2 bpair(uint u){
  union { uint u; float f; } lo, hi;
  lo.u = u << 16; hi.u = u & 0xffff0000u;
  float2 r; r.x = lo.f; r.y = hi.f; return r;
}
#define SWZ(row, col) ((col) ^ (((row) & 7) << 3))

// ---------------- fp8 e4m3 (OCP) helpers: HW cvt if available, SW fallback ----------------
__device__ __forceinline__ uchar f2e4m3_sw(float f){
  union { float f; uint u; } a; a.f = f;
  uint s = a.u >> 31; a.u &= 0x7fffffffu;
  if (a.f > 448.f) a.f = 448.f;
  uchar r;
  if (a.f < 0.0009765625f){ r = 0; }                 // < 2^-10 -> 0
  else {
    uint u = a.u; int ex = (int)(u >> 23) - 127;
    if (ex < -6){
      int q = (int)(a.f * 512.f + 0.5f); if (q > 7) q = 7;
      r = (uchar)q;
    } else {
      uint rr = u + 0x7ffffu + ((u >> 20) & 1u);     // RNE into 3-bit mantissa
      int ex2 = (int)(rr >> 23) - 127;
      uint m3 = (rr >> 20) & 7u;
      int eb = ex2 + 7;
      if (eb > 15 || (eb == 15 && m3 > 6)){ eb = 15; m3 = 6; }  // sat 448
      r = (uchar)((eb << 3) | m3);
    }
  }
  return (uchar)(r | (s << 7));
}
__device__ __forceinline__ float e4m3f_sw(uchar b){
  uint s = b >> 7, e = (b >> 3) & 15u, m = b & 7u;
  float v;
  if (e == 0) v = (float)m * 0.001953125f;           // 2^-9
  else { union { uint u; float f; } t; t.u = ((e + 120u) << 23) | (m << 20); v = t.f; }
  return s ? -v : v;
}
#if __has_builtin(__builtin_amdgcn_cvt_pk_fp8_f32)
__device__ __forceinline__ uchar f2e4m3(float f){
  uint t = (uint)__builtin_amdgcn_cvt_pk_fp8_f32(f, 0.f, 0, false);
  return (uchar)(t & 0xffu);
}
#else
__device__ __forceinline__ uchar f2e4m3(float f){ return f2e4m3_sw(f); }
#endif
#if __has_builtin(__builtin_amdgcn_cvt_pk_f32_fp8)
template<bool WORD>
__device__ __forceinline__ float2 e8pair(uint u){
  fv2 r = __builtin_amdgcn_cvt_pk_f32_fp8(u, WORD);   // WORD is a literal constant
  float2 o; o.x = r.x; o.y = r.y; return o;
}
#else
template<bool WORD>
__device__ __forceinline__ float2 e8pair(uint u){
  uint sh = WORD ? 16u : 0u;
  float2 o;
  o.x = e4m3f_sw((uchar)((u >> sh) & 0xffu));
  o.y = e4m3f_sw((uchar)((u >> (sh + 8u)) & 0xffu));
  return o;
}
#endif

// ---------------- S1: weight conv (208) + zero cnt (32) + mod layer1 (16 blocks) ----------------
__global__ __launch_bounds__(256) void s1_setup(
    const float* __restrict__ sw1, const float* __restrict__ wq, const float* __restrict__ wk,
    const float* __restrict__ wv, const float* __restrict__ wo, const float* __restrict__ fw1,
    const float* __restrict__ fw2, ushort* __restrict__ dst,
    int* __restrict__ cnt,
    const float* __restrict__ te, const float* __restrict__ mw1, const float* __restrict__ mb1,
    float* __restrict__ tbuf)
{
  const int b = blockIdx.x, tid = threadIdx.x;
  if (b < 208){
    int i = (b * 256 + tid) * 4;
    const float* src; int off;
    if      (i <  16384){ src = sw1; off = i; }
    else if (i <  32768){ src = wq;  off = i - 16384; }
    else if (i <  49152){ src = wk;  off = i - 32768; }
    else if (i <  65536){ src = wv;  off = i - 49152; }
    else if (i <  81920){ src = wo;  off = i - 65536; }
    else if (i < 147456){ src = fw1; off = i - 81920; }
    else                { src = fw2; off = i - 147456; }
    float4 v = *(const float4*)&src[off];
    ushort4 o; o.x = f2b(v.x); o.y = f2b(v.y); o.z = f2b(v.z); o.w = f2b(v.w);
    *(ushort4*)&dst[i] = o;
  } else if (b < 240){
    cnt[(b - 208) * 256 + tid] = 0;
  } else {
    const int og = tid >> 4, th = tid & 15;
    const int o = (b - 240) * 16 + og;
    float acc = 0.f;
    #pragma unroll
    for (int u = 0; u < 4; ++u){
      float4 w  = *(const float4*)&mw1[o*256 + th*16 + u*4];
      float4 t4 = *(const float4*)&te[th*16 + u*4];
      acc += w.x*t4.x + w.y*t4.y + w.z*t4.z + w.w*t4.w;
    }
    #pragma unroll
    for (int m = 1; m < 16; m <<= 1) acc += __shfl_xor(acc, m);
    if (th == 0){
      float z = acc + mb1[o];
      tbuf[o] = z / (1.f + __expf(-z));
    }
  }
}

// ---------------- K2: siren -> y (LN+mod) -> QKV via MFMA + scatter/mod blocks ----------------
// Q stored bf16; K,V stored fp8 e4m3 INTERLEAVED per row (256B) -> ONE row-gather per edge.
__global__ __launch_bounds__(512, 4) void k2_ctx_y_qkv(
    const float* __restrict__ x, const float* __restrict__ ce,
    const float* __restrict__ sw0, const float* __restrict__ sb0,
    const ushort* __restrict__ sw1b, const float* __restrict__ sb1,
    const ushort* __restrict__ wqb, const float* __restrict__ bq,
    const ushort* __restrict__ wkb, const float* __restrict__ bk,
    const ushort* __restrict__ wvb, const float* __restrict__ bv,
    const float* __restrict__ tbuf, const float* __restrict__ mw2, const float* __restrict__ mb2,
    float* __restrict__ mod,
    ushort* __restrict__ Ybf, ushort* __restrict__ Qb,
    uchar* __restrict__ KV8,
    const int* __restrict__ ei, int E, int* __restrict__ cnt, int* __restrict__ adj)
{
  __shared__ float  ceL[RT2][8];
  __shared__ float  tbL[256];
  __shared__ float  modL[256];
  __shared__ ushort hxb[RT2*CC];
  __shared__ float  yL[RT2][132];
  __shared__ ushort yb[RT2*CC];
  const int tid  = threadIdx.x;

  if (blockIdx.x >= TNODES/RT2){
    const int b2 = blockIdx.x - TNODES/RT2;
    if (b2 < (int)((E + 1023) / 1024)){
      int e0 = (b2 * 512 + tid) * 2;
      if (e0 + 1 < E){
        int4 p = *(const int4*)&ei[2*e0];
        int s;
        s = atomicAdd(&cnt[p.x], 1); adj[p.x*DEGCAP + (s & (DEGCAP-1))] = p.y;
        s = atomicAdd(&cnt[p.z], 1); adj[p.z*DEGCAP + (s & (DEGCAP-1))] = p.w;
      } else if (e0 < E){
        int sr = ei[2*e0], ds = ei[2*e0+1];
        int s = atomicAdd(&cnt[sr], 1);
        adj[sr*DEGCAP + (s & (DEGCAP-1))] = ds;
      }
    } else {
      // mod layer2 (full 384): 32 outs per block, 16 lanes each
      const int mb = b2 - (int)((E + 1023) / 1024);
      const int og = tid >> 4, th = tid & 15;
      const int o = mb*32 + og;                      // 12 blocks x 32 = 384
      float acc = 0.f;
      #pragma unroll
      for (int u = 0; u < 4; ++u){
        float4 wv = *(const float4*)&mw2[o*256 + th*16 + u*4];
        float4 t4 = *(const float4*)&tbuf[th*16 + u*4];
        acc += wv.x*t4.x + wv.y*t4.y + wv.z*t4.z + wv.w*t4.w;
      }
      #pragma unroll
      for (int m = 1; m < 16; m <<= 1) acc += __shfl_xor(acc, m);
      if (th == 0) mod[o] = acc + mb2[o];
    }
    return;
  }

  const int lane = tid & 63, wave = tid >> 6;
  const int l15 = lane & 15, lg = lane >> 4;
  const int hw  = wave & 3;          // head / col-group
  const int rtb = (wave >> 2) * 16;  // row-tile base
  const int row0 = blockIdx.x * RT2;

  if (tid < RT2*7){ int r = tid/7, i = tid - r*7; ceL[r][i] = ce[(row0+r)*7 + i]; }
  if (tid < 256) tbL[tid] = tbuf[tid];
  __syncthreads();

  // hctx = sin(ce @ sw0^T + sb0) -> bf16 LDS (swizzled): 32x128 vals, 8/thread
  #pragma unroll
  for (int u = 0; u < 8; ++u){
    int idx = tid + u*512;
    int r = idx >> 7, j = idx & 127;
    float a = sb0[j];
    #pragma unroll
    for (int i = 0; i < 7; ++i) a += sw0[j*7+i]*ceL[r][i];
    hxb[r*CC + SWZ(r, j)] = f2b(__sinf(a));
  }

  // modL2 (a,b only, private per block)
  {
    const int g = tid >> 4, th = tid & 15;
    #pragma unroll
    for (int it = 0; it < 8; ++it){
      int o = g*8 + it;
      float acc = 0.f;
      #pragma unroll
      for (int u = 0; u < 4; ++u){
        float4 wv = *(const float4*)&mw2[o*256 + th*16 + u*4];
        float4 t4 = *(const float4*)&tbL[th*16 + u*4];
        acc += wv.x*t4.x + wv.y*t4.y + wv.z*t4.z + wv.w*t4.w;
      }
      #pragma unroll
      for (int m = 1; m < 16; m <<= 1) acc += __shfl_xor(acc, m);
      if (th == 0) modL[o] = acc + mb2[o];
    }
  }
  __syncthreads();

  const int colb = hw*32;
  // y_pre = x + hctx @ sw1^T + sb1
  {
    bf8 aH[4], bB[8];
    #pragma unroll
    for (int ks = 0; ks < 4; ++ks)
      aH[ks] = *(const bf8*)&hxb[(rtb+l15)*CC + SWZ(rtb+l15, ks*32 + lg*8)];
    #pragma unroll
    for (int ks = 0; ks < 4; ++ks)
      #pragma unroll
      for (int n = 0; n < 2; ++n)
        bB[ks*2+n] = *(const bf8*)&sw1b[(colb + n*16 + l15)*CC + ks*32 + lg*8];
    fx4 acc[2]; acc[0] = 0.f; acc[1] = 0.f;
    #pragma unroll
    for (int ks = 0; ks < 4; ++ks){
      acc[0] = __builtin_amdgcn_mfma_f32_16x16x32_bf16(aH[ks], bB[ks*2+0], acc[0], 0, 0, 0);
      acc[1] = __builtin_amdgcn_mfma_f32_16x16x32_bf16(aH[ks], bB[ks*2+1], acc[1], 0, 0, 0);
    }
    #pragma unroll
    for (int n = 0; n < 2; ++n)
      #pragma unroll
      for (int q = 0; q < 4; ++q){
        int r = rtb + lg*4 + q, c = colb + n*16 + l15;
        yL[r][c] = x[(row0+r)*CC + c] + acc[n][q] + sb1[c];
      }
  }
  __syncthreads();

  // LN over 128 + (1+a)*z + b -> bf16 LDS (swizzled)
  {
    int r = tid >> 4, s16 = tid & 15;
    float4 za = *(const float4*)&yL[r][s16*8];
    float4 zb = *(const float4*)&yL[r][s16*8 + 4];
    float sum = za.x+za.y+za.z+za.w + zb.x+zb.y+zb.z+zb.w;
    float ssq = za.x*za.x+za.y*za.y+za.z*za.z+za.w*za.w
              + zb.x*zb.x+zb.y*zb.y+zb.z*zb.z+zb.w*zb.w;
    #pragma unroll
    for (int m = 1; m < 16; m <<= 1){ sum += __shfl_xor(sum, m); ssq += __shfl_xor(ssq, m); }
    float mean = sum * (1.f/128.f);
    float var  = ssq * (1.f/128.f) - mean*mean;
    float inv  = rsqrtf(var + 1e-5f);
    float zv[8] = {za.x,za.y,za.z,za.w,zb.x,zb.y,zb.z,zb.w};
    bf8 pk;
    #pragma unroll
    for (int u = 0; u < 8; ++u){
      int jj = s16*8 + u;
      float z = (zv[u] - mean) * inv;
      pk[u] = (short)f2b((1.f + modL[jj]) * z + modL[128+jj]);
    }
    *(bf8*)&yb[r*CC + SWZ(r, s16*8)] = pk;
  }
  __syncthreads();

  // store Y (bf16)
  {
    int rr = tid >> 4, b8 = tid & 15;
    bf8 v = *(const bf8*)&yb[rr*CC + SWZ(rr, b8*8)];
    *(bf8*)&Ybf[(row0+rr)*CC + b8*8] = v;
  }

  // QKV: wave = (head hw, row-tile rtb); q,k get per-head LN; Q->bf16, K/V->fp8 interleaved
  bf8 af[4];
  #pragma unroll
  for (int ks = 0; ks < 4; ++ks)
    af[ks] = *(const bf8*)&yb[(rtb+l15)*CC + SWZ(rtb+l15, ks*32 + lg*8)];

  const ushort* Wb[3] = {wqb, wkb, wvb};
  const float*  Bs[3] = {bq, bk, bv};
  const int cb = hw*32;
  #pragma unroll
  for (int m = 0; m < 3; ++m){
    bf8 bB[8];
    #pragma unroll
    for (int ks = 0; ks < 4; ++ks)
      #pragma unroll
      for (int n = 0; n < 2; ++n)
        bB[ks*2+n] = *(const bf8*)&Wb[m][(cb + n*16 + l15)*CC + ks*32 + lg*8];
    fx4 acc[2]; acc[0] = 0.f; acc[1] = 0.f;
    #pragma unroll
    for (int ks = 0; ks < 4; ++ks){
      acc[0] = __builtin_amdgcn_mfma_f32_16x16x32_bf16(af[ks], bB[ks*2+0], acc[0], 0, 0, 0);
      acc[1] = __builtin_amdgcn_mfma_f32_16x16x32_bf16(af[ks], bB[ks*2+1], acc[1], 0, 0, 0);
    }
    float vals[2][4];
    #pragma unroll
    for (int n = 0; n < 2; ++n)
      #pragma unroll
      for (int q = 0; q < 4; ++q)
        vals[n][q] = acc[n][q] + Bs[m][cb + n*16 + l15];
    if (m < 2){
      #pragma unroll
      for (int q = 0; q < 4; ++q){
        float s  = vals[0][q] + vals[1][q];
        float ss = vals[0][q]*vals[0][q] + vals[1][q]*vals[1][q];
        #pragma unroll
        for (int mm = 1; mm < 16; mm <<= 1){ s += __shfl_xor(s, mm); ss += __shfl_xor(ss, mm); }
        float mean = s * (1.f/32.f);
        float var  = ss * (1.f/32.f) - mean*mean;
        float inv  = rsqrtf(var + 1e-5f);
        vals[0][q] = (vals[0][q] - mean) * inv;
        vals[1][q] = (vals[1][q] - mean) * inv;
      }
    }
    #pragma unroll
    for (int n = 0; n < 2; ++n)
      #pragma unroll
      for (int q = 0; q < 4; ++q){
        int r = rtb + lg*4 + q, c = cb + n*16 + l15;
        if (m == 0)      Qb[(row0+r)*CC + c] = f2b(vals[n][q]);
        else if (m == 1) KV8[(row0+r)*256 + 16*(c>>3) + (c&7)]     = f2e4m3(vals[n][q]);
        else             KV8[(row0+r)*256 + 16*(c>>3) + 8 + (c&7)] = f2e4m3(vals[n][q]);
      }
  }
}

// ---------------- K45: fused-KV fp8 edge attention + wo + FFN + final mix ----------------
// RT5=16, 256 threads, 4 waves x 4 srcs. Grid 512 -> 2 blocks/CU co-resident so one
// block's FFN (compute) overlaps the other's gather (random-miss stall) — block-level
// latency hiding the compiler can't defeat. LDS ~25KB.
__global__ __launch_bounds__(256) void k45_attn_ffn(
    const float* __restrict__ x, const ushort* __restrict__ Ybf,
    const ushort* __restrict__ Qb, const uchar* __restrict__ KV8,
    const int* __restrict__ cnt, const int* __restrict__ adj,
    const ushort* __restrict__ wob, const float* __restrict__ bo,
    const ushort* __restrict__ fw1b, const float* __restrict__ fb1,
    const ushort* __restrict__ fw2b, const float* __restrict__ fb2,
    const float* __restrict__ mod, float* __restrict__ out)
{
  __shared__ float  cL[128];
  __shared__ ushort aLb[RT5*CC];
  __shared__ ushort yyb[RT5*CC];
  __shared__ ushort h1b[RT5*512];
  const int tid  = threadIdx.x;
  const int lane = tid & 63, w = tid >> 6;      // 4 waves
  const int l15 = lane & 15, lg = lane >> 4;
  const int row0 = blockIdx.x * RT5;

  if (tid < 128) cL[tid] = mod[256 + tid];
  __syncthreads();

  // ---- attention: 4 waves x 4 srcs (16 lanes each), 8-edge batched, fused KV ----
  {
    const int quarter = lane >> 4, ql = lane & 15;   // lane owns dim-group ql (dims 8ql..8ql+7)
    const int src = row0 + w*4 + quarter;

    uint4 qr = *(const uint4*)&Qb[src*CC + 8*ql];
    float2 qa = bpair(qr.x), qb = bpair(qr.y), qc = bpair(qr.z), qd = bpair(qr.w);
    const float sc = 0.17677669529663687f;           // 1/sqrt(32)
    qa.x*=sc; qa.y*=sc; qb.x*=sc; qb.y*=sc; qc.x*=sc; qc.y*=sc; qd.x*=sc; qd.y*=sc;

    float a0=0.f,a1=0.f,a2=0.f,a3=0.f,a4=0.f,a5=0.f,a6=0.f,a7=0.f, dh=0.f;
    const int deg = min(cnt[src], DEGCAP);
    const int* ab = adj + src*DEGCAP;
    int dmax = deg;
    dmax = max(dmax, __shfl_xor(dmax, 16));
    dmax = max(dmax, __shfl_xor(dmax, 32));

    // kv.x,.y = K dims 8ql..+7 ; kv.z,.w = V dims 8ql..+7
    auto dotk = [&](uint4 kv)->float{
      float2 e0 = e8pair<false>(kv.x), e1 = e8pair<true>(kv.x);
      float2 e2 = e8pair<false>(kv.y), e3 = e8pair<true>(kv.y);
      return qa.x*e0.x+qa.y*e0.y + qb.x*e1.x+qb.y*e1.y + qc.x*e2.x+qc.y*e2.y + qd.x*e3.x+qd.y*e3.y;
    };
    auto accv = [&](uint4 kv, float p){
      float2 e0 = e8pair<false>(kv.z), e1 = e8pair<true>(kv.z);
      float2 e2 = e8pair<false>(kv.w), e3 = e8pair<true>(kv.w);
      a0 += p*e0.x; a1 += p*e0.y; a2 += p*e1.x; a3 += p*e1.y;
      a4 += p*e2.x; a5 += p*e2.y; a6 += p*e3.x; a7 += p*e3.y;
    };

    for (int e = 0; e < dmax; e += 8){
      int4 dA = *(const int4*)&ab[e];
      int4 dB = *(const int4*)&ab[e+4];
      int d0 = (e   < deg) ? dA.x : 0;
      int d1 = (e+1 < deg) ? dA.y : 0;
      int d2 = (e+2 < deg) ? dA.z : 0;
      int d3 = (e+3 < deg) ? dA.w : 0;
      int d4 = (e+4 < deg) ? dB.x : 0;
      int d5 = (e+5 < deg) ? dB.y : 0;
      int d6 = (e+6 < deg) ? dB.z : 0;
      int d7 = (e+7 < deg) ? dB.w : 0;
      // one 16B load per edge: both K and V fragments
      uint4 kv0 = *(const uint4*)&KV8[d0*256 + 16*ql];
      uint4 kv1 = *(const uint4*)&KV8[d1*256 + 16*ql];
      uint4 kv2 = *(const uint4*)&KV8[d2*256 + 16*ql];
      uint4 kv3 = *(const uint4*)&KV8[d3*256 + 16*ql];
      uint4 kv4 = *(const uint4*)&KV8[d4*256 + 16*ql];
      uint4 kv5 = *(const uint4*)&KV8[d5*256 + 16*ql];
      uint4 kv6 = *(const uint4*)&KV8[d6*256 + 16*ql];
      uint4 kv7 = *(const uint4*)&KV8[d7*256 + 16*ql];

      float p0 = dotk(kv0), p1 = dotk(kv1), p2 = dotk(kv2), p3 = dotk(kv3);
      float p4 = dotk(kv4), p5 = dotk(kv5), p6 = dotk(kv6), p7 = dotk(kv7);
      p0 += __shfl_xor(p0, 1); p1 += __shfl_xor(p1, 1); p2 += __shfl_xor(p2, 1); p3 += __shfl_xor(p3, 1);
      p4 += __shfl_xor(p4, 1); p5 += __shfl_xor(p5, 1); p6 += __shfl_xor(p6, 1); p7 += __shfl_xor(p7, 1);
      p0 += __shfl_xor(p0, 2); p1 += __shfl_xor(p1, 2); p2 += __shfl_xor(p2, 2); p3 += __shfl_xor(p3, 2);
      p4 += __shfl_xor(p4, 2); p5 += __shfl_xor(p5, 2); p6 += __shfl_xor(p6, 2); p7 += __shfl_xor(p7, 2);
      p0 = (e   < deg) ? __expf(p0) : 0.f;
      p1 = (e+1 < deg) ? __expf(p1) : 0.f;
      p2 = (e+2 < deg) ? __expf(p2) : 0.f;
      p3 = (e+3 < deg) ? __expf(p3) : 0.f;
      p4 = (e+4 < deg) ? __expf(p4) : 0.f;
      p5 = (e+5 < deg) ? __expf(p5) : 0.f;
      p6 = (e+6 < deg) ? __expf(p6) : 0.f;
      p7 = (e+7 < deg) ? __expf(p7) : 0.f;
      accv(kv0, p0); accv(kv1, p1); accv(kv2, p2); accv(kv3, p3);
      accv(kv4, p4); accv(kv5, p5); accv(kv6, p6); accv(kv7, p7);
      dh += p0 + p1 + p2 + p3 + p4 + p5 + p6 + p7;
    }
    float invd = 1.f / fmaxf(dh, 1e-9f);
    uint4 o4;
    o4.x = (uint)f2b(a0*invd) | ((uint)f2b(a1*invd) << 16);
    o4.y = (uint)f2b(a2*invd) | ((uint)f2b(a3*invd) << 16);
    o4.z = (uint)f2b(a4*invd) | ((uint)f2b(a5*invd) << 16);
    o4.w = (uint)f2b(a6*invd) | ((uint)f2b(a7*invd) << 16);
    int r = w*4 + quarter;
    *(uint4*)&aLb[r*CC + SWZ(r, 8*ql)] = o4;
  }
  __syncthreads();

  // ---- wo GEMM: wave w owns cols w*32..w*32+31, rows 0..15 (A from LDS) ----
  {
    const int colb = w*32;
    bf8 aA[4], bB[8];
    #pragma unroll
    for (int ks = 0; ks < 4; ++ks)
      aA[ks] = *(const bf8*)&aLb[l15*CC + SWZ(l15, ks*32 + lg*8)];
    #pragma unroll
    for (int ks = 0; ks < 4; ++ks)
      #pragma unroll
      for (int n = 0; n < 2; ++n)
        bB[ks*2+n] = *(const bf8*)&wob[(colb + n*16 + l15)*CC + ks*32 + lg*8];
    fx4 acc[2]; acc[0] = 0.f; acc[1] = 0.f;
    #pragma unroll
    for (int ks = 0; ks < 4; ++ks){
      acc[0] = __builtin_amdgcn_mfma_f32_16x16x32_bf16(aA[ks], bB[ks*2+0], acc[0], 0, 0, 0);
      acc[1] = __builtin_amdgcn_mfma_f32_16x16x32_bf16(aA[ks], bB[ks*2+1], acc[1], 0, 0, 0);
    }
    #pragma unroll
    for (int n = 0; n < 2; ++n)
      #pragma unroll
      for (int q = 0; q < 4; ++q){
        int r = lg*4 + q, c = colb + n*16 + l15;
        float yy = b2f(Ybf[(row0+r)*CC + c]) + acc[n][q] + bo[c];
        yyb[r*CC + SWZ(r, c)] = f2b(yy);
      }
  }
  __syncthreads();

  // ---- fw1 + silu: wave w owns cols w*128..w*128+127, rows 0..15 ----
  {
    const int cb1 = w*128;
    bf8 aY[4];
    #pragma unroll
    for (int ks = 0; ks < 4; ++ks)
      aY[ks] = *(const bf8*)&yyb[l15*CC + SWZ(l15, ks*32 + lg*8)];
    fx4 h[8];
    #pragma unroll
    for (int n = 0; n < 8; ++n) h[n] = 0.f;
    #pragma unroll
    for (int g = 0; g < 2; ++g){
      #pragma unroll
      for (int kp = 0; kp < 2; ++kp){
        bf8 bB[8];
        #pragma unroll
        for (int kk = 0; kk < 2; ++kk)
          #pragma unroll
          for (int n = 0; n < 4; ++n)
            bB[kk*4+n] = *(const bf8*)&fw1b[(cb1 + (g*4+n)*16 + l15)*CC + (kp*2+kk)*32 + lg*8];
        #pragma unroll
        for (int kk = 0; kk < 2; ++kk)
          #pragma unroll
          for (int n = 0; n < 4; ++n)
            h[g*4+n] = __builtin_amdgcn_mfma_f32_16x16x32_bf16(aY[kp*2+kk], bB[kk*4+n], h[g*4+n], 0, 0, 0);
      }
    }
    #pragma unroll
    for (int n = 0; n < 8; ++n)
      #pragma unroll
      for (int q = 0; q < 4; ++q){
        int r = lg*4 + q, c = cb1 + n*16 + l15;
        float z = h[n][q] + fb1[c];
        float sl = z / (1.f + __expf(-z));
        h1b[r*512 + SWZ(r, c)] = f2b(sl);
      }
  }
  __syncthreads();

  // ---- fw2: wave w owns cols w*32..w*32+31, K=512 ----
  {
    const int colb = w*32;
    fx4 acc[2]; acc[0] = 0.f; acc[1] = 0.f;
    #pragma unroll
    for (int g4 = 0; g4 < 4; ++g4){
      bf8 aH[4], bB[8];
      #pragma unroll
      for (int kk = 0; kk < 4; ++kk)
        aH[kk] = *(const bf8*)&h1b[l15*512 + SWZ(l15, (g4*4+kk)*32 + lg*8)];
      #pragma unroll
      for (int kk = 0; kk < 4; ++kk)
        #pragma unroll
        for (int n = 0; n < 2; ++n)
          bB[kk*2+n] = *(const bf8*)&fw2b[(colb + n*16 + l15)*512 + (g4*4+kk)*32 + lg*8];
      #pragma unroll
      for (int kk = 0; kk < 4; ++kk){
        acc[0] = __builtin_amdgcn_mfma_f32_16x16x32_bf16(aH[kk], bB[kk*2+0], acc[0], 0, 0, 0);
        acc[1] = __builtin_amdgcn_mfma_f32_16x16x32_bf16(aH[kk], bB[kk*2+1], acc[1], 0, 0, 0);
      }
    }
    #pragma unroll
    for (int n = 0; n < 2; ++n)
      #pragma unroll
      for (int q = 0; q < 4; ++q){
        int r = lg*4 + q, c = colb + n*16 + l15;
        int g = row0 + r;
        float cj = cL[c];
        float y2 = acc[n][q] + fb2[c];
        out[g*CC + c] = (x[g*CC + c] + cj*y2) * rsqrtf(1.f + cj*cj);
      }
  }
}

extern "C" void kernel_launch(void* const* d_in, const int* in_sizes, int n_in,
                              void* d_out, int out_size, void* d_ws, size_t ws_size,
                              hipStream_t stream)
{
  const float* x   = (const float*)d_in[0];
  const float* te  = (const float*)d_in[1];
  const float* ce  = (const float*)d_in[2];
  const int*   ei  = (const int*)  d_in[3];
  const float* mw1 = (const float*)d_in[4];
  const float* mb1 = (const float*)d_in[5];
  const float* mw2 = (const float*)d_in[6];
  const float* mb2 = (const float*)d_in[7];
  const float* sw0 = (const float*)d_in[8];
  const float* sb0 = (const float*)d_in[9];
  const float* sw1 = (const float*)d_in[10];
  const float* sb1 = (const float*)d_in[11];
  const float* wq  = (const float*)d_in[12];
  const float* bq  = (const float*)d_in[13];
  const float* wk  = (const float*)d_in[14];
  const float* bk  = (const float*)d_in[15];
  const float* wv  = (const float*)d_in[16];
  const float* bv  = (const float*)d_in[17];
  const float* wo  = (const float*)d_in[18];
  const float* bo  = (const float*)d_in[19];
  const float* fw1 = (const float*)d_in[20];
  const float* fb1 = (const float*)d_in[21];
  const float* fw2 = (const float*)d_in[22];
  const float* fb2 = (const float*)d_in[23];
  float* out = (float*)d_out;
  const int E = in_sizes[3] / 2;

  float* ws   = (float*)d_ws;
  float* tbuf = ws;                           // 256 (pad 512)
  float* mod  = ws + 512;                     // 384 (pad 512)
  ushort* WB  = (ushort*)(ws + 1024);         // 212992 bf16 weights
  ushort* sw1b = WB;
  ushort* wqb  = WB + 16384;
  ushort* wkb  = WB + 32768;
  ushort* wvb  = WB + 49152;
  ushort* wob  = WB + 65536;
  ushort* fw1b = WB + 81920;
  ushort* fw2b = WB + 147456;
  ushort* Ybf = WB + 212992;                  // TN*CC bf16
  ushort* Qb  = Ybf + TNODES*CC;              // TN*CC bf16
  uchar*  KV8 = (uchar*)(Qb + TNODES*CC);     // TN*256 fp8 interleaved K|V
  int* cnt    = (int*)(KV8 + TNODES*256);     // TN counts
  int* adj    = cnt + TNODES;                 // TN*DEGCAP bucket adjacency

  const int nSB = (E + 1023) / 1024;

  s1_setup<<<256, 256, 0, stream>>>(sw1, wq, wk, wv, wo, fw1, fw2, WB, cnt, te, mw1, mb1, tbuf);
  k2_ctx_y_qkv<<<TNODES/RT2 + nSB + 12, 512, 0, stream>>>(x, ce, sw0, sb0, sw1b, sb1,
                                              wqb, bq, wkb, bk, wvb, bv,
                                              tbuf, mw2, mb2, mod, Ybf, Qb, KV8,
                                              ei, E, cnt, adj);
  k45_attn_ffn<<<TNODES/RT5, 256, 0, stream>>>(x, Ybf, Qb, KV8, cnt, adj,
                                               wob, bo, fw1b, fb1, fw2b, fb2,
                                               mod, out);
}

// Round 19
// 64.840 us; speedup vs baseline: 1.1353x; 1.1353x over previous
//
#include <hip/hip_runtime.h>
#include <math.h>

#define TNODES 8192
#define CC 128
#define RT2 32       // rows per block for k2 (512 threads, 8 waves)
#define RT5 32       // srcs per block for k45 (512 threads, 8 waves x 4 srcs)
#define DEGCAP 128   // bucket capacity per src; degrees ~Poisson(39)+1, max~70

typedef __attribute__((ext_vector_type(8))) short bf8;
typedef __attribute__((ext_vector_type(4))) float fx4;
typedef __attribute__((ext_vector_type(2))) float fv2;

__device__ __forceinline__ ushort f2b(float f){
  union { float f; uint u; } a; a.f = f;
  uint u = a.u;
  uint r = (u + 0x7fffu + ((u >> 16) & 1u)) >> 16;   // RNE
  return (ushort)r;
}
__device__ __forceinline__ float b2f(ushort s){
  union { uint u; float f; } a; a.u = ((uint)s) << 16;
  return a.f;
}
__device__ __forceinline__ float2 bpair(uint u){
  union { uint u; float f; } lo, hi;
  lo.u = u << 16; hi.u = u & 0xffff0000u;
  float2 r; r.x = lo.f; r.y = hi.f; return r;
}
#define SWZ(row, col) ((col) ^ (((row) & 7) << 3))

// ---------------- fp8 e4m3 (OCP) helpers: HW cvt if available, SW fallback ----------------
__device__ __forceinline__ uchar f2e4m3_sw(float f){
  union { float f; uint u; } a; a.f = f;
  uint s = a.u >> 31; a.u &= 0x7fffffffu;
  if (a.f > 448.f) a.f = 448.f;
  uchar r;
  if (a.f < 0.0009765625f){ r = 0; }                 // < 2^-10 -> 0
  else {
    uint u = a.u; int ex = (int)(u >> 23) - 127;
    if (ex < -6){
      int q = (int)(a.f * 512.f + 0.5f); if (q > 7) q = 7;
      r = (uchar)q;
    } else {
      uint rr = u + 0x7ffffu + ((u >> 20) & 1u);     // RNE into 3-bit mantissa
      int ex2 = (int)(rr >> 23) - 127;
      uint m3 = (rr >> 20) & 7u;
      int eb = ex2 + 7;
      if (eb > 15 || (eb == 15 && m3 > 6)){ eb = 15; m3 = 6; }  // sat 448
      r = (uchar)((eb << 3) | m3);
    }
  }
  return (uchar)(r | (s << 7));
}
__device__ __forceinline__ float e4m3f_sw(uchar b){
  uint s = b >> 7, e = (b >> 3) & 15u, m = b & 7u;
  float v;
  if (e == 0) v = (float)m * 0.001953125f;           // 2^-9
  else { union { uint u; float f; } t; t.u = ((e + 120u) << 23) | (m << 20); v = t.f; }
  return s ? -v : v;
}
#if __has_builtin(__builtin_amdgcn_cvt_pk_fp8_f32)
__device__ __forceinline__ uchar f2e4m3(float f){
  uint t = (uint)__builtin_amdgcn_cvt_pk_fp8_f32(f, 0.f, 0, false);
  return (uchar)(t & 0xffu);
}
#else
__device__ __forceinline__ uchar f2e4m3(float f){ return f2e4m3_sw(f); }
#endif
#if __has_builtin(__builtin_amdgcn_cvt_pk_f32_fp8)
template<bool WORD>
__device__ __forceinline__ float2 e8pair(uint u){
  fv2 r = __builtin_amdgcn_cvt_pk_f32_fp8(u, WORD);   // WORD is a literal constant
  float2 o; o.x = r.x; o.y = r.y; return o;
}
#else
template<bool WORD>
__device__ __forceinline__ float2 e8pair(uint u){
  uint sh = WORD ? 16u : 0u;
  float2 o;
  o.x = e4m3f_sw((uchar)((u >> sh) & 0xffu));
  o.y = e4m3f_sw((uchar)((u >> (sh + 8u)) & 0xffu));
  return o;
}
#endif

// ---------------- S1: weight conv (208) + zero cnt (32) + mod layer1 (16 blocks) ----------------
__global__ __launch_bounds__(256) void s1_setup(
    const float* __restrict__ sw1, const float* __restrict__ wq, const float* __restrict__ wk,
    const float* __restrict__ wv, const float* __restrict__ wo, const float* __restrict__ fw1,
    const float* __restrict__ fw2, ushort* __restrict__ dst,
    int* __restrict__ cnt,
    const float* __restrict__ te, const float* __restrict__ mw1, const float* __restrict__ mb1,
    float* __restrict__ tbuf)
{
  const int b = blockIdx.x, tid = threadIdx.x;
  if (b < 208){
    int i = (b * 256 + tid) * 4;
    const float* src; int off;
    if      (i <  16384){ src = sw1; off = i; }
    else if (i <  32768){ src = wq;  off = i - 16384; }
    else if (i <  49152){ src = wk;  off = i - 32768; }
    else if (i <  65536){ src = wv;  off = i - 49152; }
    else if (i <  81920){ src = wo;  off = i - 65536; }
    else if (i < 147456){ src = fw1; off = i - 81920; }
    else                { src = fw2; off = i - 147456; }
    float4 v = *(const float4*)&src[off];
    ushort4 o; o.x = f2b(v.x); o.y = f2b(v.y); o.z = f2b(v.z); o.w = f2b(v.w);
    *(ushort4*)&dst[i] = o;
  } else if (b < 240){
    cnt[(b - 208) * 256 + tid] = 0;
  } else {
    const int og = tid >> 4, th = tid & 15;
    const int o = (b - 240) * 16 + og;
    float acc = 0.f;
    #pragma unroll
    for (int u = 0; u < 4; ++u){
      float4 w  = *(const float4*)&mw1[o*256 + th*16 + u*4];
      float4 t4 = *(const float4*)&te[th*16 + u*4];
      acc += w.x*t4.x + w.y*t4.y + w.z*t4.z + w.w*t4.w;
    }
    #pragma unroll
    for (int m = 1; m < 16; m <<= 1) acc += __shfl_xor(acc, m);
    if (th == 0){
      float z = acc + mb1[o];
      tbuf[o] = z / (1.f + __expf(-z));
    }
  }
}

// ---------------- K2: siren -> y (LN+mod) -> QKV via MFMA + scatter/mod blocks ----------------
// Q stored bf16; K,V stored fp8 e4m3 INTERLEAVED per row (256B: per dim-group g of 8,
// bytes [16g..16g+8) = K dims, [16g+8..16g+16) = V dims) -> ONE 256B row-gather per edge.
__global__ __launch_bounds__(512, 4) void k2_ctx_y_qkv(
    const float* __restrict__ x, const float* __restrict__ ce,
    const float* __restrict__ sw0, const float* __restrict__ sb0,
    const ushort* __restrict__ sw1b, const float* __restrict__ sb1,
    const ushort* __restrict__ wqb, const float* __restrict__ bq,
    const ushort* __restrict__ wkb, const float* __restrict__ bk,
    const ushort* __restrict__ wvb, const float* __restrict__ bv,
    const float* __restrict__ tbuf, const float* __restrict__ mw2, const float* __restrict__ mb2,
    float* __restrict__ mod,
    ushort* __restrict__ Ybf, ushort* __restrict__ Qb,
    uchar* __restrict__ KV8,
    const int* __restrict__ ei, int E, int* __restrict__ cnt, int* __restrict__ adj)
{
  __shared__ float  ceL[RT2][8];
  __shared__ float  tbL[256];
  __shared__ float  modL[256];
  __shared__ ushort hxb[RT2*CC];
  __shared__ float  yL[RT2][132];
  __shared__ ushort yb[RT2*CC];
  const int tid  = threadIdx.x;

  if (blockIdx.x >= TNODES/RT2){
    const int b2 = blockIdx.x - TNODES/RT2;
    if (b2 < (int)((E + 1023) / 1024)){
      int e0 = (b2 * 512 + tid) * 2;
      if (e0 + 1 < E){
        int4 p = *(const int4*)&ei[2*e0];
        int s;
        s = atomicAdd(&cnt[p.x], 1); adj[p.x*DEGCAP + (s & (DEGCAP-1))] = p.y;
        s = atomicAdd(&cnt[p.z], 1); adj[p.z*DEGCAP + (s & (DEGCAP-1))] = p.w;
      } else if (e0 < E){
        int sr = ei[2*e0], ds = ei[2*e0+1];
        int s = atomicAdd(&cnt[sr], 1);
        adj[sr*DEGCAP + (s & (DEGCAP-1))] = ds;
      }
    } else {
      // mod layer2 (full 384): 32 outs per block, 16 lanes each
      const int mb = b2 - (int)((E + 1023) / 1024);
      const int og = tid >> 4, th = tid & 15;
      const int o = mb*32 + og;                      // 12 blocks x 32 = 384
      float acc = 0.f;
      #pragma unroll
      for (int u = 0; u < 4; ++u){
        float4 wv = *(const float4*)&mw2[o*256 + th*16 + u*4];
        float4 t4 = *(const float4*)&tbuf[th*16 + u*4];
        acc += wv.x*t4.x + wv.y*t4.y + wv.z*t4.z + wv.w*t4.w;
      }
      #pragma unroll
      for (int m = 1; m < 16; m <<= 1) acc += __shfl_xor(acc, m);
      if (th == 0) mod[o] = acc + mb2[o];
    }
    return;
  }

  const int lane = tid & 63, wave = tid >> 6;
  const int l15 = lane & 15, lg = lane >> 4;
  const int hw  = wave & 3;          // head / col-group
  const int rtb = (wave >> 2) * 16;  // row-tile base
  const int row0 = blockIdx.x * RT2;

  if (tid < RT2*7){ int r = tid/7, i = tid - r*7; ceL[r][i] = ce[(row0+r)*7 + i]; }
  if (tid < 256) tbL[tid] = tbuf[tid];
  __syncthreads();

  // hctx = sin(ce @ sw0^T + sb0) -> bf16 LDS (swizzled): 32x128 vals, 8/thread
  #pragma unroll
  for (int u = 0; u < 8; ++u){
    int idx = tid + u*512;
    int r = idx >> 7, j = idx & 127;
    float a = sb0[j];
    #pragma unroll
    for (int i = 0; i < 7; ++i) a += sw0[j*7+i]*ceL[r][i];
    hxb[r*CC + SWZ(r, j)] = f2b(__sinf(a));
  }

  // modL2 (a,b only, private per block)
  {
    const int g = tid >> 4, th = tid & 15;
    #pragma unroll
    for (int it = 0; it < 8; ++it){
      int o = g*8 + it;
      float acc = 0.f;
      #pragma unroll
      for (int u = 0; u < 4; ++u){
        float4 wv = *(const float4*)&mw2[o*256 + th*16 + u*4];
        float4 t4 = *(const float4*)&tbL[th*16 + u*4];
        acc += wv.x*t4.x + wv.y*t4.y + wv.z*t4.z + wv.w*t4.w;
      }
      #pragma unroll
      for (int m = 1; m < 16; m <<= 1) acc += __shfl_xor(acc, m);
      if (th == 0) modL[o] = acc + mb2[o];
    }
  }
  __syncthreads();

  const int colb = hw*32;
  // y_pre = x + hctx @ sw1^T + sb1
  {
    bf8 aH[4], bB[8];
    #pragma unroll
    for (int ks = 0; ks < 4; ++ks)
      aH[ks] = *(const bf8*)&hxb[(rtb+l15)*CC + SWZ(rtb+l15, ks*32 + lg*8)];
    #pragma unroll
    for (int ks = 0; ks < 4; ++ks)
      #pragma unroll
      for (int n = 0; n < 2; ++n)
        bB[ks*2+n] = *(const bf8*)&sw1b[(colb + n*16 + l15)*CC + ks*32 + lg*8];
    fx4 acc[2]; acc[0] = 0.f; acc[1] = 0.f;
    #pragma unroll
    for (int ks = 0; ks < 4; ++ks){
      acc[0] = __builtin_amdgcn_mfma_f32_16x16x32_bf16(aH[ks], bB[ks*2+0], acc[0], 0, 0, 0);
      acc[1] = __builtin_amdgcn_mfma_f32_16x16x32_bf16(aH[ks], bB[ks*2+1], acc[1], 0, 0, 0);
    }
    #pragma unroll
    for (int n = 0; n < 2; ++n)
      #pragma unroll
      for (int q = 0; q < 4; ++q){
        int r = rtb + lg*4 + q, c = colb + n*16 + l15;
        yL[r][c] = x[(row0+r)*CC + c] + acc[n][q] + sb1[c];
      }
  }
  __syncthreads();

  // LN over 128 + (1+a)*z + b -> bf16 LDS (swizzled)
  {
    int r = tid >> 4, s16 = tid & 15;
    float4 za = *(const float4*)&yL[r][s16*8];
    float4 zb = *(const float4*)&yL[r][s16*8 + 4];
    float sum = za.x+za.y+za.z+za.w + zb.x+zb.y+zb.z+zb.w;
    float ssq = za.x*za.x+za.y*za.y+za.z*za.z+za.w*za.w
              + zb.x*zb.x+zb.y*zb.y+zb.z*zb.z+zb.w*zb.w;
    #pragma unroll
    for (int m = 1; m < 16; m <<= 1){ sum += __shfl_xor(sum, m); ssq += __shfl_xor(ssq, m); }
    float mean = sum * (1.f/128.f);
    float var  = ssq * (1.f/128.f) - mean*mean;
    float inv  = rsqrtf(var + 1e-5f);
    float zv[8] = {za.x,za.y,za.z,za.w,zb.x,zb.y,zb.z,zb.w};
    bf8 pk;
    #pragma unroll
    for (int u = 0; u < 8; ++u){
      int jj = s16*8 + u;
      float z = (zv[u] - mean) * inv;
      pk[u] = (short)f2b((1.f + modL[jj]) * z + modL[128+jj]);
    }
    *(bf8*)&yb[r*CC + SWZ(r, s16*8)] = pk;
  }
  __syncthreads();

  // store Y (bf16)
  {
    int rr = tid >> 4, b8 = tid & 15;
    bf8 v = *(const bf8*)&yb[rr*CC + SWZ(rr, b8*8)];
    *(bf8*)&Ybf[(row0+rr)*CC + b8*8] = v;
  }

  // QKV: wave = (head hw, row-tile rtb); q,k get per-head LN; Q->bf16, K/V->fp8 interleaved
  bf8 af[4];
  #pragma unroll
  for (int ks = 0; ks < 4; ++ks)
    af[ks] = *(const bf8*)&yb[(rtb+l15)*CC + SWZ(rtb+l15, ks*32 + lg*8)];

  const ushort* Wb[3] = {wqb, wkb, wvb};
  const float*  Bs[3] = {bq, bk, bv};
  const int cb = hw*32;
  #pragma unroll
  for (int m = 0; m < 3; ++m){
    bf8 bB[8];
    #pragma unroll
    for (int ks = 0; ks < 4; ++ks)
      #pragma unroll
      for (int n = 0; n < 2; ++n)
        bB[ks*2+n] = *(const bf8*)&Wb[m][(cb + n*16 + l15)*CC + ks*32 + lg*8];
    fx4 acc[2]; acc[0] = 0.f; acc[1] = 0.f;
    #pragma unroll
    for (int ks = 0; ks < 4; ++ks){
      acc[0] = __builtin_amdgcn_mfma_f32_16x16x32_bf16(af[ks], bB[ks*2+0], acc[0], 0, 0, 0);
      acc[1] = __builtin_amdgcn_mfma_f32_16x16x32_bf16(af[ks], bB[ks*2+1], acc[1], 0, 0, 0);
    }
    float vals[2][4];
    #pragma unroll
    for (int n = 0; n < 2; ++n)
      #pragma unroll
      for (int q = 0; q < 4; ++q)
        vals[n][q] = acc[n][q] + Bs[m][cb + n*16 + l15];
    if (m < 2){
      #pragma unroll
      for (int q = 0; q < 4; ++q){
        float s  = vals[0][q] + vals[1][q];
        float ss = vals[0][q]*vals[0][q] + vals[1][q]*vals[1][q];
        #pragma unroll
        for (int mm = 1; mm < 16; mm <<= 1){ s += __shfl_xor(s, mm); ss += __shfl_xor(ss, mm); }
        float mean = s * (1.f/32.f);
        float var  = ss * (1.f/32.f) - mean*mean;
        float inv  = rsqrtf(var + 1e-5f);
        vals[0][q] = (vals[0][q] - mean) * inv;
        vals[1][q] = (vals[1][q] - mean) * inv;
      }
    }
    #pragma unroll
    for (int n = 0; n < 2; ++n)
      #pragma unroll
      for (int q = 0; q < 4; ++q){
        int r = rtb + lg*4 + q, c = cb + n*16 + l15;
        if (m == 0)      Qb[(row0+r)*CC + c] = f2b(vals[n][q]);
        else if (m == 1) KV8[(row0+r)*256 + 16*(c>>3) + (c&7)]     = f2e4m3(vals[n][q]);
        else             KV8[(row0+r)*256 + 16*(c>>3) + 8 + (c&7)] = f2e4m3(vals[n][q]);
      }
  }
}

// ---------------- K45: fused-KV fp8 edge attention + wo + FFN + final mix ----------------
// RT5=32, 512 threads, 8 waves x 4 srcs. ONE uint4/lane (16B) per edge covers both the
// K and V fragments (256B row) — halves the random row-gather count vs separate K/V.
__global__ __launch_bounds__(512) void k45_attn_ffn(
    const float* __restrict__ x, const ushort* __restrict__ Ybf,
    const ushort* __restrict__ Qb, const uchar* __restrict__ KV8,
    const int* __restrict__ cnt, const int* __restrict__ adj,
    const ushort* __restrict__ wob, const float* __restrict__ bo,
    const ushort* __restrict__ fw1b, const float* __restrict__ fb1,
    const ushort* __restrict__ fw2b, const float* __restrict__ fb2,
    const float* __restrict__ mod, float* __restrict__ out)
{
  __shared__ float  cL[128];
  __shared__ ushort aLb[RT5*CC];
  __shared__ ushort yyb[RT5*CC];
  __shared__ ushort h1b[RT5*512];
  const int tid  = threadIdx.x;
  const int lane = tid & 63, w = tid >> 6;      // 8 waves
  const int l15 = lane & 15, lg = lane >> 4;
  const int row0 = blockIdx.x * RT5;

  if (tid < 128) cL[tid] = mod[256 + tid];
  __syncthreads();

  // ---- attention: 8 waves x 4 srcs (16 lanes each), 8-edge batched, fused KV ----
  {
    const int quarter = lane >> 4, ql = lane & 15;   // lane owns dim-group ql (dims 8ql..8ql+7)
    const int src = row0 + w*4 + quarter;

    uint4 qr = *(const uint4*)&Qb[src*CC + 8*ql];
    float2 qa = bpair(qr.x), qb = bpair(qr.y), qc = bpair(qr.z), qd = bpair(qr.w);
    const float sc = 0.17677669529663687f;           // 1/sqrt(32)
    qa.x*=sc; qa.y*=sc; qb.x*=sc; qb.y*=sc; qc.x*=sc; qc.y*=sc; qd.x*=sc; qd.y*=sc;

    float a0=0.f,a1=0.f,a2=0.f,a3=0.f,a4=0.f,a5=0.f,a6=0.f,a7=0.f, dh=0.f;
    const int deg = min(cnt[src], DEGCAP);
    const int* ab = adj + src*DEGCAP;
    int dmax = deg;
    dmax = max(dmax, __shfl_xor(dmax, 16));
    dmax = max(dmax, __shfl_xor(dmax, 32));

    // kv.x,.y = K dims 8ql..+7 ; kv.z,.w = V dims 8ql..+7
    auto dotk = [&](uint4 kv)->float{
      float2 e0 = e8pair<false>(kv.x), e1 = e8pair<true>(kv.x);
      float2 e2 = e8pair<false>(kv.y), e3 = e8pair<true>(kv.y);
      return qa.x*e0.x+qa.y*e0.y + qb.x*e1.x+qb.y*e1.y + qc.x*e2.x+qc.y*e2.y + qd.x*e3.x+qd.y*e3.y;
    };
    auto accv = [&](uint4 kv, float p){
      float2 e0 = e8pair<false>(kv.z), e1 = e8pair<true>(kv.z);
      float2 e2 = e8pair<false>(kv.w), e3 = e8pair<true>(kv.w);
      a0 += p*e0.x; a1 += p*e0.y; a2 += p*e1.x; a3 += p*e1.y;
      a4 += p*e2.x; a5 += p*e2.y; a6 += p*e3.x; a7 += p*e3.y;
    };

    for (int e = 0; e < dmax; e += 8){
      int4 dA = *(const int4*)&ab[e];
      int4 dB = *(const int4*)&ab[e+4];
      int d0 = (e   < deg) ? dA.x : 0;
      int d1 = (e+1 < deg) ? dA.y : 0;
      int d2 = (e+2 < deg) ? dA.z : 0;
      int d3 = (e+3 < deg) ? dA.w : 0;
      int d4 = (e+4 < deg) ? dB.x : 0;
      int d5 = (e+5 < deg) ? dB.y : 0;
      int d6 = (e+6 < deg) ? dB.z : 0;
      int d7 = (e+7 < deg) ? dB.w : 0;
      // one 16B load per edge: both K and V fragments
      uint4 kv0 = *(const uint4*)&KV8[d0*256 + 16*ql];
      uint4 kv1 = *(const uint4*)&KV8[d1*256 + 16*ql];
      uint4 kv2 = *(const uint4*)&KV8[d2*256 + 16*ql];
      uint4 kv3 = *(const uint4*)&KV8[d3*256 + 16*ql];
      uint4 kv4 = *(const uint4*)&KV8[d4*256 + 16*ql];
      uint4 kv5 = *(const uint4*)&KV8[d5*256 + 16*ql];
      uint4 kv6 = *(const uint4*)&KV8[d6*256 + 16*ql];
      uint4 kv7 = *(const uint4*)&KV8[d7*256 + 16*ql];

      float p0 = dotk(kv0), p1 = dotk(kv1), p2 = dotk(kv2), p3 = dotk(kv3);
      float p4 = dotk(kv4), p5 = dotk(kv5), p6 = dotk(kv6), p7 = dotk(kv7);
      p0 += __shfl_xor(p0, 1); p1 += __shfl_xor(p1, 1); p2 += __shfl_xor(p2, 1); p3 += __shfl_xor(p3, 1);
      p4 += __shfl_xor(p4, 1); p5 += __shfl_xor(p5, 1); p6 += __shfl_xor(p6, 1); p7 += __shfl_xor(p7, 1);
      p0 += __shfl_xor(p0, 2); p1 += __shfl_xor(p1, 2); p2 += __shfl_xor(p2, 2); p3 += __shfl_xor(p3, 2);
      p4 += __shfl_xor(p4, 2); p5 += __shfl_xor(p5, 2); p6 += __shfl_xor(p6, 2); p7 += __shfl_xor(p7, 2);
      p0 = (e   < deg) ? __expf(p0) : 0.f;
      p1 = (e+1 < deg) ? __expf(p1) : 0.f;
      p2 = (e+2 < deg) ? __expf(p2) : 0.f;
      p3 = (e+3 < deg) ? __expf(p3) : 0.f;
      p4 = (e+4 < deg) ? __expf(p4) : 0.f;
      p5 = (e+5 < deg) ? __expf(p5) : 0.f;
      p6 = (e+6 < deg) ? __expf(p6) : 0.f;
      p7 = (e+7 < deg) ? __expf(p7) : 0.f;
      accv(kv0, p0); accv(kv1, p1); accv(kv2, p2); accv(kv3, p3);
      accv(kv4, p4); accv(kv5, p5); accv(kv6, p6); accv(kv7, p7);
      dh += p0 + p1 + p2 + p3 + p4 + p5 + p6 + p7;
    }
    float invd = 1.f / fmaxf(dh, 1e-9f);
    uint4 o4;
    o4.x = (uint)f2b(a0*invd) | ((uint)f2b(a1*invd) << 16);
    o4.y = (uint)f2b(a2*invd) | ((uint)f2b(a3*invd) << 16);
    o4.z = (uint)f2b(a4*invd) | ((uint)f2b(a5*invd) << 16);
    o4.w = (uint)f2b(a6*invd) | ((uint)f2b(a7*invd) << 16);
    int r = w*4 + quarter;
    *(uint4*)&aLb[r*CC + SWZ(r, 8*ql)] = o4;
  }
  __syncthreads();

  // ---- wo GEMM: wave w owns cols w*16, rows 0..31 (A from LDS) ----
  {
    const int cw = w*16;
    bf8 aA[2][4], bB[4];
    #pragma unroll
    for (int rt = 0; rt < 2; ++rt)
      #pragma unroll
      for (int ks = 0; ks < 4; ++ks)
        aA[rt][ks] = *(const bf8*)&aLb[(rt*16+l15)*CC + SWZ(rt*16+l15, ks*32 + lg*8)];
    #pragma unroll
    for (int ks = 0; ks < 4; ++ks)
      bB[ks] = *(const bf8*)&wob[(cw + l15)*CC + ks*32 + lg*8];
    fx4 acc[2]; acc[0] = 0.f; acc[1] = 0.f;
    #pragma unroll
    for (int ks = 0; ks < 4; ++ks){
      acc[0] = __builtin_amdgcn_mfma_f32_16x16x32_bf16(aA[0][ks], bB[ks], acc[0], 0, 0, 0);
      acc[1] = __builtin_amdgcn_mfma_f32_16x16x32_bf16(aA[1][ks], bB[ks], acc[1], 0, 0, 0);
    }
    #pragma unroll
    for (int rt = 0; rt < 2; ++rt)
      #pragma unroll
      for (int q = 0; q < 4; ++q){
        int r = rt*16 + lg*4 + q, c = cw + l15;
        float yy = b2f(Ybf[(row0+r)*CC + c]) + acc[rt][q] + bo[c];
        yyb[r*CC + SWZ(r, c)] = f2b(yy);
      }
  }
  __syncthreads();

  // ---- fw1 + silu: wave w owns cols w*64..w*64+63, rows 0..31 ----
  {
    const int cb1 = w*64;
    bf8 aY[2][4];
    #pragma unroll
    for (int rt = 0; rt < 2; ++rt)
      #pragma unroll
      for (int ks = 0; ks < 4; ++ks)
        aY[rt][ks] = *(const bf8*)&yyb[(rt*16+l15)*CC + SWZ(rt*16+l15, ks*32 + lg*8)];
    fx4 h[2][4];
    #pragma unroll
    for (int rt = 0; rt < 2; ++rt)
      #pragma unroll
      for (int n = 0; n < 4; ++n) h[rt][n] = 0.f;
    #pragma unroll
    for (int kp = 0; kp < 2; ++kp){
      bf8 bB[8];
      #pragma unroll
      for (int kk = 0; kk < 2; ++kk)
        #pragma unroll
        for (int n = 0; n < 4; ++n)
          bB[kk*4+n] = *(const bf8*)&fw1b[(cb1 + n*16 + l15)*CC + (kp*2+kk)*32 + lg*8];
      #pragma unroll
      for (int kk = 0; kk < 2; ++kk)
        #pragma unroll
        for (int n = 0; n < 4; ++n){
          h[0][n] = __builtin_amdgcn_mfma_f32_16x16x32_bf16(aY[0][kp*2+kk], bB[kk*4+n], h[0][n], 0, 0, 0);
          h[1][n] = __builtin_amdgcn_mfma_f32_16x16x32_bf16(aY[1][kp*2+kk], bB[kk*4+n], h[1][n], 0, 0, 0);
        }
    }
    #pragma unroll
    for (int rt = 0; rt < 2; ++rt)
      #pragma unroll
      for (int n = 0; n < 4; ++n)
        #pragma unroll
        for (int q = 0; q < 4; ++q){
          int r = rt*16 + lg*4 + q, c = cb1 + n*16 + l15;
          float z = h[rt][n][q] + fb1[c];
          float sl = z / (1.f + __expf(-z));
          h1b[r*512 + SWZ(r, c)] = f2b(sl);
        }
  }
  __syncthreads();

  // ---- fw2: wave w owns cols w*16, K=512 ----
  {
    const int cw = w*16;
    fx4 acc[2]; acc[0] = 0.f; acc[1] = 0.f;
    #pragma unroll
    for (int g4 = 0; g4 < 4; ++g4){
      bf8 aH[2][4], bB[4];
      #pragma unroll
      for (int rt = 0; rt < 2; ++rt)
        #pragma unroll
        for (int kk = 0; kk < 4; ++kk)
          aH[rt][kk] = *(const bf8*)&h1b[(rt*16+l15)*512 + SWZ(rt*16+l15, (g4*4+kk)*32 + lg*8)];
      #pragma unroll
      for (int kk = 0; kk < 4; ++kk)
        bB[kk] = *(const bf8*)&fw2b[(cw + l15)*512 + (g4*4+kk)*32 + lg*8];
      #pragma unroll
      for (int kk = 0; kk < 4; ++kk){
        acc[0] = __builtin_amdgcn_mfma_f32_16x16x32_bf16(aH[0][kk], bB[kk], acc[0], 0, 0, 0);
        acc[1] = __builtin_amdgcn_mfma_f32_16x16x32_bf16(aH[1][kk], bB[kk], acc[1], 0, 0, 0);
      }
    }
    #pragma unroll
    for (int rt = 0; rt < 2; ++rt)
      #pragma unroll
      for (int q = 0; q < 4; ++q){
        int r = rt*16 + lg*4 + q, c = cw + l15;
        int g = row0 + r;
        float cj = cL[c];
        float y2 = acc[rt][q] + fb2[c];
        out[g*CC + c] = (x[g*CC + c] + cj*y2) * rsqrtf(1.f + cj*cj);
      }
  }
}

extern "C" void kernel_launch(void* const* d_in, const int* in_sizes, int n_in,
                              void* d_out, int out_size, void* d_ws, size_t ws_size,
                              hipStream_t stream)
{
  const float* x   = (const float*)d_in[0];
  const float* te  = (const float*)d_in[1];
  const float* ce  = (const float*)d_in[2];
  const int*   ei  = (const int*)  d_in[3];
  const float* mw1 = (const float*)d_in[4];
  const float* mb1 = (const float*)d_in[5];
  const float* mw2 = (const float*)d_in[6];
  const float* mb2 = (const float*)d_in[7];
  const float* sw0 = (const float*)d_in[8];
  const float* sb0 = (const float*)d_in[9];
  const float* sw1 = (const float*)d_in[10];
  const float* sb1 = (const float*)d_in[11];
  const float* wq  = (const float*)d_in[12];
  const float* bq  = (const float*)d_in[13];
  const float* wk  = (const float*)d_in[14];
  const float* bk  = (const float*)d_in[15];
  const float* wv  = (const float*)d_in[16];
  const float* bv  = (const float*)d_in[17];
  const float* wo  = (const float*)d_in[18];
  const float* bo  = (const float*)d_in[19];
  const float* fw1 = (const float*)d_in[20];
  const float* fb1 = (const float*)d_in[21];
  const float* fw2 = (const float*)d_in[22];
  const float* fb2 = (const float*)d_in[23];
  float* out = (float*)d_out;
  const int E = in_sizes[3] / 2;

  float* ws   = (float*)d_ws;
  float* tbuf = ws;                           // 256 (pad 512)
  float* mod  = ws + 512;                     // 384 (pad 512)
  ushort* WB  = (ushort*)(ws + 1024);         // 212992 bf16 weights
  ushort* sw1b = WB;
  ushort* wqb  = WB + 16384;
  ushort* wkb  = WB + 32768;
  ushort* wvb  = WB + 49152;
  ushort* wob  = WB + 65536;
  ushort* fw1b = WB + 81920;
  ushort* fw2b = WB + 147456;
  ushort* Ybf = WB + 212992;                  // TN*CC bf16
  ushort* Qb  = Ybf + TNODES*CC;              // TN*CC bf16
  uchar*  KV8 = (uchar*)(Qb + TNODES*CC);     // TN*256 fp8 interleaved K|V
  int* cnt    = (int*)(KV8 + TNODES*256);     // TN counts
  int* adj    = cnt + TNODES;                 // TN*DEGCAP bucket adjacency

  const int nSB = (E + 1023) / 1024;

  s1_setup<<<256, 256, 0, stream>>>(sw1, wq, wk, wv, wo, fw1, fw2, WB, cnt, te, mw1, mb1, tbuf);
  k2_ctx_y_qkv<<<TNODES/RT2 + nSB + 12, 512, 0, stream>>>(x, ce, sw0, sb0, sw1b, sb1,
                                              wqb, bq, wkb, bk, wvb, bv,
                                              tbuf, mw2, mb2, mod, Ybf, Qb, KV8,
                                              ei, E, cnt, adj);
  k45_attn_ffn<<<TNODES/RT5, 512, 0, stream>>>(x, Ybf, Qb, KV8, cnt, adj,
                                               wob, bo, fw1b, fb1, fw2b, fb2,
                                               mod, out);
}